// Round 4
// baseline (679.034 us; speedup 1.0000x reference)
//
#include <hip/hip_runtime.h>
#include <hip/hip_bf16.h>
#include <cstdint>

typedef __attribute__((ext_vector_type(8))) __bf16 bf16x8;
typedef __attribute__((ext_vector_type(8))) unsigned short u16x8;
typedef __attribute__((ext_vector_type(4))) float f32x4;

#define QKSTRIDE 640
#define QKROW 1280
#define VTPAD 528
#define KSTEP (64 * QKROW * 2)

static __device__ __forceinline__ unsigned short f2bf(float f) {
  __hip_bfloat16 h = __float2bfloat16(f);
  return *reinterpret_cast<unsigned short*>(&h);
}
static __device__ __forceinline__ unsigned pack2bf(float a, float b) {
  return (unsigned)f2bf(a) | ((unsigned)f2bf(b) << 16);
}

static __device__ __forceinline__ void gload_lds16(const void* g, void* lds) {
  __builtin_amdgcn_global_load_lds(
      (const __attribute__((address_space(1))) unsigned int*)g,
      (__attribute__((address_space(3))) unsigned int*)lds, 16, 0, 0);
}

// inline-asm 16B global load: compiler does NOT track it in waitcnt bookkeeping,
// so our counted s_waitcnt vmcnt(N) governs (T4 pattern).
static __device__ __forceinline__ bf16x8 gload16(const void* p) {
  bf16x8 r;
  asm volatile("global_load_dwordx4 %0, %1, off" : "=v"(r) : "v"(p) : "memory");
  return r;
}

// ---------------- prep: head dims, loss, column map, block schedule ----------------
__global__ void prep_kernel(const float* __restrict__ logits, int* __restrict__ hdr,
                            int* __restrict__ cmap, int* __restrict__ sched,
                            float* __restrict__ loss_out) {
  if (threadIdx.x != 0 || blockIdx.x != 0) return;
  float l[6]; float mx = -1e30f;
  for (int i = 0; i < 6; ++i) { l[i] = logits[i]; mx = fmaxf(mx, l[i]); }
  float e[6]; float s = 0.f;
  for (int i = 0; i < 6; ++i) { e[i] = expf(l[i] - mx); s += e[i]; }
  float hdf[6]; float sumh = 0.f;
  for (int i = 0; i < 6; ++i) { hdf[i] = 8.0f + (e[i] / s) * 464.0f; sumh += hdf[i]; }
  int hdi[6]; float res[6]; int isum = 0;
  for (int i = 0; i < 6; ++i) {
    float fl = floorf(hdf[i]);
    hdi[i] = (int)fl; res[i] = hdf[i] - fl; isum += hdi[i];
  }
  int diff = 512 - isum;
  bool used[6] = {false, false, false, false, false, false};
  if (diff > 0) {
    for (int t = 0; t < diff; ++t) {
      int best = -1; float bv = -1e30f;
      for (int i = 0; i < 6; ++i) if (!used[i] && res[i] > bv) { bv = res[i]; best = i; }
      used[best] = true; hdi[best] += 1;
    }
  } else if (diff < 0) {
    for (int t = 0; t < -diff; ++t) {
      int best = -1; float bv = 1e30f;
      for (int i = 0; i < 6; ++i) if (!used[i] && res[i] < bv) { bv = res[i]; best = i; }
      used[best] = true; hdi[best] -= 1;
    }
  }
  int starts[6], astarts[6];
  { int st = 0, ast = 0;
    for (int i = 0; i < 6; ++i) {
      starts[i] = st; astarts[i] = ast;
      hdr[i] = hdi[i]; hdr[8 + i] = st; hdr[16 + i] = ast;
      st += hdi[i]; ast += (hdi[i] + 7) & ~7;
    } }
  for (int col = 0; col < 512; ++col) {
    int hh = 5;
    for (int i = 0; i < 5; ++i) if (col < starts[i + 1]) { hh = i; break; }
    int qc = astarts[hh] + (col - starts[hh]);
    cmap[col] = qc;
    cmap[512 + col] = QKSTRIDE + qc;
    cmap[1024 + col] = 4096 + col;
  }
  // ---- block schedule: 24 (h,b) work-sets, LPT into 8 XCD bins of 3, big-first ----
  {
    int csth[6];
    for (int i = 0; i < 6; ++i) {
      int ncl = (hdi[i] + 31) / 32;
      int ntl = (hdi[i] + 15) / 16;
      csth[i] = 4 * ncl + 2 * ntl + 8;
    }
    int ord[6] = {0, 1, 2, 3, 4, 5};
    for (int a = 0; a < 6; ++a)
      for (int c = a + 1; c < 6; ++c)
        if (csth[ord[c]] > csth[ord[a]]) { int t = ord[a]; ord[a] = ord[c]; ord[c] = t; }
    int binload[8], bincnt[8], binh[8][3], binb[8][3];
    for (int x = 0; x < 8; ++x) { binload[x] = 0; bincnt[x] = 0; }
    for (int a = 0; a < 6; ++a)
      for (int bb = 0; bb < 4; ++bb) {
        int best = -1;
        for (int x = 0; x < 8; ++x)
          if (bincnt[x] < 3 && (best < 0 || binload[x] < binload[best])) best = x;
        binh[best][bincnt[best]] = ord[a];
        binb[best][bincnt[best]] = bb;
        binload[best] += csth[ord[a]];
        bincnt[best]++;
      }
    for (int x = 0; x < 8; ++x)
      for (int pI = 0; pI < 3; ++pI)
        for (int q = 0; q < 32; ++q)
          sched[x + 8 * (pI * 32 + q)] = binh[x][pI] | (binb[x][pI] << 4) | (q << 8);
  }
  float dv = sumh - 512.0f;
  float floss = dv * dv;
  float rsum = 0.f;
  for (int i = 0; i < 6; ++i) rsum += fmaxf(8.0f - hdf[i], 0.0f);
  floss += rsum / 6.0f;
  float il = 0.f;
  for (int i = 0; i < 6; ++i) { float dd = hdf[i] - (float)hdi[i]; il += dd * dd; }
  il /= 6.0f;
  loss_out[0] = floss + 0.5f * il;
}

// ---------------- converters ----------------
__global__ void conv_bf16_kernel(const float* __restrict__ x, unsigned short* __restrict__ y, int n4) {
  int i = blockIdx.x * blockDim.x + threadIdx.x;
  if (i >= n4) return;
  float4 v = reinterpret_cast<const float4*>(x)[i];
  union { unsigned short u[4]; uint2 q; } o;
  o.u[0] = f2bf(v.x); o.u[1] = f2bf(v.y); o.u[2] = f2bf(v.z); o.u[3] = f2bf(v.w);
  reinterpret_cast<uint2*>(y)[i] = o.q;
}

__global__ void convWT_kernel(const float* __restrict__ W, unsigned short* __restrict__ WT, int N) {
  int idx = blockIdx.x * blockDim.x + threadIdx.x;
  if (idx >= N * 512) return;
  int k = idx & 511, n = idx >> 9;
  WT[idx] = f2bf(W[(size_t)k * N + n]);
}

// ---------------- GEMM: C[M][N] = A[M][K](bf16) @ Bt[N][K]^T + bias ----------------
template<int MODE>
__global__ __launch_bounds__(256, 2) void gemm_bt(
    const unsigned short* __restrict__ A,
    const unsigned short* __restrict__ Bt,
    const float* __restrict__ bias,
    float* __restrict__ Cf,
    unsigned short* __restrict__ qkpad,
    unsigned short* __restrict__ vbuf,
    const int* __restrict__ cmap,
    int N, int K)
{
  __shared__ unsigned short As[128 * 32];
  __shared__ unsigned short Bs[128 * 32];
  const int tid = threadIdx.x;
  const int wave = tid >> 6, lane = tid & 63;
  const int lrow = lane & 15, lgrp = lane >> 4;
  const int wm = wave >> 1, wn = wave & 1;
  const int brow = blockIdx.y * 128;
  const int bcol = blockIdx.x * 128;

  f32x4 acc[4][4];
#pragma unroll
  for (int m = 0; m < 4; ++m)
#pragma unroll
    for (int n = 0; n < 4; ++n) acc[m][n] = (f32x4){0.f, 0.f, 0.f, 0.f};

  const int sig0 = wave * 128 + lane;
  for (int kb = 0; kb < K; kb += 32) {
    __syncthreads();
#pragma unroll
    for (int it = 0; it < 2; ++it) {
      const int sigma = sig0 + it * 64;
      const int r = sigma >> 2, sp = sigma & 3;
      const int sl = sp ^ ((r >> 1) & 3);
      gload_lds16(&A[(size_t)(brow + r) * K + kb + sl * 8], &As[sigma * 8]);
    }
#pragma unroll
    for (int it = 0; it < 2; ++it) {
      const int sigma = sig0 + it * 64;
      const int r = sigma >> 2, sp = sigma & 3;
      const int sl = sp ^ ((r >> 1) & 3);
      gload_lds16(&Bt[(size_t)(bcol + r) * K + kb + sl * 8], &Bs[sigma * 8]);
    }
    __syncthreads();
    const int sub = (lgrp ^ ((lrow >> 1) & 3)) * 8;
    bf16x8 aF[4], bF[4];
#pragma unroll
    for (int m = 0; m < 4; ++m)
      aF[m] = *reinterpret_cast<const bf16x8*>(&As[(wm * 64 + m * 16 + lrow) * 32 + sub]);
#pragma unroll
    for (int n = 0; n < 4; ++n)
      bF[n] = *reinterpret_cast<const bf16x8*>(&Bs[(wn * 64 + n * 16 + lrow) * 32 + sub]);
#pragma unroll
    for (int m = 0; m < 4; ++m)
#pragma unroll
      for (int n = 0; n < 4; ++n)
        acc[m][n] = __builtin_amdgcn_mfma_f32_16x16x32_bf16(aF[m], bF[n], acc[m][n], 0, 0, 0);
  }

#pragma unroll
  for (int n = 0; n < 4; ++n) {
    const int col = bcol + wn * 64 + n * 16 + lrow;
    const float bv = bias[col];
    int mc = 0;
    if (MODE == 1) mc = cmap[col];
#pragma unroll
    for (int m = 0; m < 4; ++m) {
#pragma unroll
      for (int r = 0; r < 4; ++r) {
        const int row = brow + wm * 64 + m * 16 + lgrp * 4 + r;
        const float v = acc[m][n][r] + bv;
        if (MODE == 0) {
          Cf[(size_t)row * N + col] = v;
        } else {
          if (mc < 4096) qkpad[(size_t)row * QKROW + mc] = f2bf(v);
          else vbuf[(size_t)row * 512 + (mc - 4096)] = f2bf(v);
        }
      }
    }
  }
}

// ---------------- V transpose ----------------
__global__ void transV_kernel(const unsigned short* __restrict__ vbuf, unsigned short* __restrict__ Vt) {
  __shared__ unsigned short tile[64][33];
  const int b = blockIdx.z, c0 = blockIdx.y * 32, t0 = blockIdx.x * 64;
  const int i = threadIdx.x;
  {
    int r = i >> 2, cc = (i & 3) * 8;
    u16x8 v = *reinterpret_cast<const u16x8*>(&vbuf[(size_t)(b * 2048 + t0 + r) * 512 + c0 + cc]);
#pragma unroll
    for (int j = 0; j < 8; ++j) tile[r][cc + j] = v[j];
  }
  __syncthreads();
  {
    int c = i >> 3, tt = (i & 7) * 8;
    u16x8 v;
#pragma unroll
    for (int j = 0; j < 8; ++j) v[j] = tile[tt + j][c];
    *reinterpret_cast<u16x8*>(&Vt[(size_t)(b * VTPAD + c0 + c) * 2048 + t0 + tt]) = v;
  }
}

// ---------------- flash attention: swapped QK^T, KVBLK=64, counted vmcnt ----------------
// Per iter: [V chunk0 x16 asm] vmcnt(16) barrier | QK(LDS) softmax(in-reg) |
// lgkm(0) vmcnt(0) PV0 | [V chunk1 x16][K-stage x8] vmcnt(8) PV1 | barrier.
// K-stage is never force-drained; all global loads are asm/builtin so the
// compiler inserts no vmcnt of its own inside the loop.
__global__ __launch_bounds__(256, 2) void attn_staged(
    const unsigned short* __restrict__ qkpad,
    const unsigned short* __restrict__ Vt,
    unsigned short* __restrict__ attnC,
    const int* __restrict__ hdr,
    const int* __restrict__ sched)
{
  const int sv = sched[blockIdx.x];
  const int h = sv & 15, b = (sv >> 4) & 15, qb = sv >> 8;
  const int d = hdr[h];
  const int nc = (d + 31) >> 5;
  if (nc > 8) return;
  const int start = hdr[8 + h];
  const int astart = hdr[16 + h];
  const int tid = threadIdx.x;
  const int wave = tid >> 6, lane = tid & 63;
  const int lrow = lane & 15, lgrp = lane >> 4;
  const int q0 = qb * 64 + wave * 16;
  const int ntiles = (d + 15) >> 4;
  const float scale = 1.0f / sqrtf((float)d);

  const int S = (4 * nc + 7) & ~7;        // K 16B-slots per row
  const int M = 64 * S;                   // slots per 64-row tile
  const float invS = 1.0f / (float)S;
  const int rowBytesK = S * 16;

  __shared__ __align__(16) unsigned char KsB[2][32768];  // 64 rows x 32 slots x 16B
  __shared__ unsigned int Pl[4][16][36];                 // per-wave P rows (padded)

  // ---- Q fragments via asm loads (B-frag: row=q=lrow, d=lgrp*8+j) ----
  bf16x8 qf[8];
  {
    const unsigned short* qp = qkpad + (size_t)(b * 2048 + q0 + lrow) * QKROW + astart + lgrp * 8;
#pragma unroll
    for (int dc = 0; dc < 8; ++dc)
      if (dc < nc) qf[dc] = gload16(qp + dc * 32);
  }
  asm volatile("s_waitcnt vmcnt(0)" ::: "memory");
  __builtin_amdgcn_sched_barrier(0);
#pragma unroll
  for (int dc = 0; dc < 8; ++dc) {
    if (dc < nc) {
#pragma unroll
      for (int j = 0; j < 8; ++j)
        if (dc * 32 + lgrp * 8 + j >= d) qf[dc][j] = (__bf16)0.0f;
    }
  }

  // ---- precomputed staging addresses (hoisted out of the loop) ----
  const char* kGbase = (const char*)qkpad;
  unsigned kOff[8]; unsigned kDst[8];
#pragma unroll
  for (int j = 0; j < 8; ++j) {
    int gg = wave * 64 + lane + 256 * j;
    if (gg >= M) gg -= M;
    if (gg >= M) gg -= M;
    if (gg >= M) gg -= M;
    const int r = (int)(((float)gg + 0.5f) * invS);
    const int p = gg - r * S;
    const int sp = p ^ (r & 7);
    kOff[j] = (unsigned)(((b * 2048 + r) * QKROW + QKSTRIDE + astart + sp * 8) * 2);
    kDst[j] = (unsigned)(gg * 16);
  }
  const char* vGbase = (const char*)Vt;
  unsigned vOff[16];
#pragma unroll
  for (int t = 0; t < 16; ++t) {
    const int vr = start + ((t < ntiles) ? (t * 16 + lrow) : lrow);
    vOff[t] = (unsigned)(((b * VTPAD + vr) * 2048 + lgrp * 8) * 2);
  }

  f32x4 acc[16];
#pragma unroll
  for (int t = 0; t < 16; ++t) acc[t] = (f32x4){0.f, 0.f, 0.f, 0.f};
  float m_run = -1e30f, l_run = 0.f;   // per-lane: own q-row = lane&15

  // prologue: stage kt=0 into buf0
#pragma unroll
  for (int j = 0; j < 8; ++j)
    gload_lds16(kGbase + kOff[j], &KsB[0][0] + kDst[j]);
#pragma unroll
  for (int j = 0; j < 8; ++j) kOff[j] += KSTEP;

  for (int i = 0; i < 32; ++i) {
    const int kt = i << 6;
    const int cur = i & 1;
    const unsigned koffb = (unsigned)(kt * 2);

    // [A] V chunk0 loads (fixed 16)
    bf16x8 vf[16];
#pragma unroll
    for (int t = 0; t < 16; ++t) vf[t] = gload16(vGbase + (size_t)(vOff[t] + koffb));

    // [C] prev K-stage done (16 V remain in flight)
    asm volatile("s_waitcnt vmcnt(16)" ::: "memory");
    __builtin_amdgcn_sched_barrier(0);
    __builtin_amdgcn_s_barrier();
    __builtin_amdgcn_sched_barrier(0);

    // ---- QK^T swapped: s = K x Q; lane holds q-row=lrow, k = 16t+lgrp*4+r ----
    f32x4 s4[4];
#pragma unroll
    for (int t = 0; t < 4; ++t) s4[t] = (f32x4){0.f, 0.f, 0.f, 0.f};
    const char* kB = (const char*)&KsB[cur][0];
    const int swz = lrow & 7;
    __builtin_amdgcn_s_setprio(1);
#pragma unroll
    for (int dc = 0; dc < 8; ++dc) {
      if (dc < nc) {
        const int phys = ((dc * 4 + lgrp) ^ swz) * 16;
#pragma unroll
        for (int t = 0; t < 4; ++t) {
          const bf16x8 kf = *reinterpret_cast<const bf16x8*>(kB + (t * 16 + lrow) * rowBytesK + phys);
          s4[t] = __builtin_amdgcn_mfma_f32_16x16x32_bf16(kf, qf[dc], s4[t], 0, 0, 0);
        }
      }
    }
    __builtin_amdgcn_s_setprio(0);

    // ---- in-register online softmax (own q-row; defer-max THR=8) ----
    float ps[16];
#pragma unroll
    for (int t = 0; t < 4; ++t)
#pragma unroll
      for (int r = 0; r < 4; ++r) ps[t * 4 + r] = s4[t][r] * scale;
    float pm = ps[0];
#pragma unroll
    for (int z = 1; z < 16; ++z) pm = fmaxf(pm, ps[z]);
    pm = fmaxf(pm, __shfl_xor(pm, 16));
    pm = fmaxf(pm, __shfl_xor(pm, 32));
    if (__any(pm > m_run + 8.0f)) {
      const float mn = fmaxf(m_run, pm);
      const float alpha = __expf(m_run - mn);
      m_run = mn;
      l_run *= alpha;
      float al4[4];
#pragma unroll
      for (int r = 0; r < 4; ++r) al4[r] = __shfl(alpha, lgrp * 4 + r);
#pragma unroll
      for (int t = 0; t < 16; ++t) {
        if (t < ntiles) {
#pragma unroll
          for (int r = 0; r < 4; ++r) acc[t][r] *= al4[r];
        }
      }
    }
    float sum = 0.f;
#pragma unroll
    for (int z = 0; z < 16; ++z) { ps[z] = __expf(ps[z] - m_run); sum += ps[z]; }
    sum += __shfl_xor(sum, 16);
    sum += __shfl_xor(sum, 32);
    l_run += sum;

    // ---- P pack -> LDS bounce (pairs; k/2 slot = 8t+2m+rp) ----
    unsigned int* Pw = &Pl[wave][lrow][0];
#pragma unroll
    for (int t = 0; t < 4; ++t) {
      uint2 w;
      w.x = pack2bf(ps[t * 4 + 0], ps[t * 4 + 1]);
      w.y = pack2bf(ps[t * 4 + 2], ps[t * 4 + 3]);
      *reinterpret_cast<uint2*>(&Pw[8 * t + 2 * lgrp]) = w;
    }
    asm volatile("s_waitcnt lgkmcnt(0)" ::: "memory");
    __builtin_amdgcn_sched_barrier(0);

    // [F] V chunk0 done (nothing else in flight)
    asm volatile("s_waitcnt vmcnt(0)" ::: "memory");
    __builtin_amdgcn_sched_barrier(0);

    // ---- PV chunk0 (k = kt..kt+31) ----
    const bf16x8 pa0 = *reinterpret_cast<const bf16x8*>(&Pl[wave][lrow][4 * lgrp]);
    __builtin_amdgcn_s_setprio(1);
#pragma unroll
    for (int t = 0; t < 16; ++t)
      if (t < ntiles) acc[t] = __builtin_amdgcn_mfma_f32_16x16x32_bf16(pa0, vf[t], acc[t], 0, 0, 0);
    __builtin_amdgcn_s_setprio(0);

    // [G] V chunk1 loads (fixed 16), then [B] K-stage next (fixed 8)
#pragma unroll
    for (int t = 0; t < 16; ++t) vf[t] = gload16(vGbase + (size_t)(vOff[t] + koffb + 64));
    {
      char* kd = (char*)&KsB[cur ^ 1][0];
#pragma unroll
      for (int j = 0; j < 8; ++j) gload_lds16(kGbase + kOff[j], kd + kDst[j]);
      if (i < 30) {
#pragma unroll
        for (int j = 0; j < 8; ++j) kOff[j] += KSTEP;
      }
    }

    // [H] V chunk1 done; K-stage (newest 8) stays in flight
    asm volatile("s_waitcnt vmcnt(8)" ::: "memory");
    __builtin_amdgcn_sched_barrier(0);

    // ---- PV chunk1 (k = kt+32..kt+63) ----
    const bf16x8 pa1 = *reinterpret_cast<const bf16x8*>(&Pl[wave][lrow][16 + 4 * lgrp]);
    __builtin_amdgcn_s_setprio(1);
#pragma unroll
    for (int t = 0; t < 16; ++t)
      if (t < ntiles) acc[t] = __builtin_amdgcn_mfma_f32_16x16x32_bf16(pa1, vf[t], acc[t], 0, 0, 0);
    __builtin_amdgcn_s_setprio(0);

    __builtin_amdgcn_s_barrier();   // [J] protect Ks[cur] before next overwrite
  }
  asm volatile("s_waitcnt vmcnt(0)" ::: "memory");  // drain trailing stage before exit

  // ---- epilogue: acc rows q = lgrp*4+r, cols d = t*16+lrow ----
  float invl[4];
#pragma unroll
  for (int r = 0; r < 4; ++r) invl[r] = 1.0f / __shfl(l_run, lgrp * 4 + r);
#pragma unroll
  for (int t = 0; t < 16; ++t) {
    if (t < ntiles) {
      const int col = t * 16 + lrow;
      if (col < d) {
#pragma unroll
        for (int r = 0; r < 4; ++r) {
          attnC[(size_t)(b * 2048 + q0 + lgrp * 4 + r) * 512 + start + col] =
              f2bf(acc[t][r] * invl[r]);
        }
      }
    }
  }
}

// ---------------- direct fallback for nc>8 (d>256), normally all-exit ----------------
template<int NCLO, int NCHI>
__global__ __launch_bounds__(256, 2) void attn_kernel(
    const unsigned short* __restrict__ qkpad,
    const unsigned short* __restrict__ Vt,
    unsigned short* __restrict__ attnC,
    const int* __restrict__ hdr)
{
  const int h = blockIdx.y, b = blockIdx.z;
  const int d = hdr[h];
  const int nc = (d + 31) >> 5;
  if (nc <= NCLO || nc > NCHI) return;
  const int start = hdr[8 + h];
  const int astart = hdr[16 + h];
  const int wave = threadIdx.x >> 6;
  const int lane = threadIdx.x & 63;
  const int lrow = lane & 15, lgrp = lane >> 4;
  const int q0 = blockIdx.x * 64 + wave * 16;
  const int ntiles = (d + 15) >> 4;
  const float scale = 1.0f / sqrtf((float)d);

  __shared__ unsigned short Pl[2][4][16 * 32];

  bf16x8 qf[NCHI];
  {
    const size_t qbase = (size_t)(b * 2048 + q0 + lrow) * QKROW + astart;
#pragma unroll
    for (int dc = 0; dc < NCHI; ++dc) {
      if (dc < nc) {
        bf16x8 v = *reinterpret_cast<const bf16x8*>(&qkpad[qbase + dc * 32 + lgrp * 8]);
#pragma unroll
        for (int j = 0; j < 8; ++j)
          if (dc * 32 + lgrp * 8 + j >= d) v[j] = (__bf16)0.0f;
        qf[dc] = v;
      }
    }
  }

  f32x4 acc[2 * NCHI];
#pragma unroll
  for (int t = 0; t < 2 * NCHI; ++t) acc[t] = (f32x4){0.f, 0.f, 0.f, 0.f};
  float m_run[4] = {-1e30f, -1e30f, -1e30f, -1e30f};
  float l_run[4] = {0.f, 0.f, 0.f, 0.f};

  for (int kt = 0; kt < 2048; kt += 32) {
    f32x4 s0 = {0.f, 0.f, 0.f, 0.f}, s1 = {0.f, 0.f, 0.f, 0.f};
    const size_t kb0 = (size_t)(b * 2048 + kt + lrow) * QKROW + QKSTRIDE + astart;
    const size_t kb1 = kb0 + (size_t)16 * QKROW;
#pragma unroll
    for (int dc = 0; dc < NCHI; ++dc) {
      if (dc < nc) {
        bf16x8 k0 = *reinterpret_cast<const bf16x8*>(&qkpad[kb0 + dc * 32 + lgrp * 8]);
        bf16x8 k1 = *reinterpret_cast<const bf16x8*>(&qkpad[kb1 + dc * 32 + lgrp * 8]);
        s0 = __builtin_amdgcn_mfma_f32_16x16x32_bf16(qf[dc], k0, s0, 0, 0, 0);
        s1 = __builtin_amdgcn_mfma_f32_16x16x32_bf16(qf[dc], k1, s1, 0, 0, 0);
      }
    }
    float p0[4], p1[4], pmax[4];
#pragma unroll
    for (int r = 0; r < 4; ++r) {
      p0[r] = s0[r] * scale; p1[r] = s1[r] * scale;
      float mx = fmaxf(p0[r], p1[r]);
#pragma unroll
      for (int off = 1; off < 16; off <<= 1) mx = fmaxf(mx, __shfl_xor(mx, off));
      pmax[r] = mx;
    }
    bool need = false;
#pragma unroll
    for (int r = 0; r < 4; ++r) need = need || (pmax[r] > m_run[r] + 8.0f);
    if (__any(need)) {
#pragma unroll
      for (int r = 0; r < 4; ++r) {
        float mn = fmaxf(m_run[r], pmax[r]);
        float al = __expf(m_run[r] - mn);
        m_run[r] = mn; l_run[r] *= al;
#pragma unroll
        for (int t = 0; t < 2 * NCHI; ++t)
          if (t < ntiles) acc[t][r] *= al;
      }
    }
#pragma unroll
    for (int r = 0; r < 4; ++r) {
      p0[r] = __expf(p0[r] - m_run[r]);
      p1[r] = __expf(p1[r] - m_run[r]);
      float sm = p0[r] + p1[r];
#pragma unroll
      for (int off = 1; off < 16; off <<= 1) sm += __shfl_xor(sm, off);
      l_run[r] += sm;
    }
    const int pb = (kt >> 5) & 1;
    unsigned short* P = &Pl[pb][wave][0];
#pragma unroll
    for (int r = 0; r < 4; ++r) {
      P[(lgrp * 4 + r) * 32 + lrow] = f2bf(p0[r]);
      P[(lgrp * 4 + r) * 32 + 16 + lrow] = f2bf(p1[r]);
    }
    asm volatile("s_waitcnt lgkmcnt(0)" ::: "memory");
    bf16x8 pf = *reinterpret_cast<const bf16x8*>(&P[lrow * 32 + lgrp * 8]);
    const size_t vbase = (size_t)(b * VTPAD + start) * 2048 + kt + lgrp * 8;
#pragma unroll
    for (int t = 0; t < 2 * NCHI; ++t) {
      if (t < ntiles) {
        bf16x8 vf = *reinterpret_cast<const bf16x8*>(&Vt[vbase + (size_t)(t * 16 + lrow) * 2048]);
        acc[t] = __builtin_amdgcn_mfma_f32_16x16x32_bf16(pf, vf, acc[t], 0, 0, 0);
      }
    }
  }

  float inv[4];
#pragma unroll
  for (int r = 0; r < 4; ++r) inv[r] = 1.0f / l_run[r];
#pragma unroll
  for (int t = 0; t < 2 * NCHI; ++t) {
    if (t < ntiles) {
      int col = t * 16 + lrow;
      if (col < d) {
#pragma unroll
        for (int r = 0; r < 4; ++r) {
          attnC[(size_t)(b * 2048 + q0 + lgrp * 4 + r) * 512 + start + col] =
              f2bf(acc[t][r] * inv[r]);
        }
      }
    }
  }
}

// ---------------- launch ----------------
extern "C" void kernel_launch(void* const* d_in, const int* in_sizes, int n_in,
                              void* d_out, int out_size, void* d_ws, size_t ws_size,
                              hipStream_t stream) {
  const float* query  = (const float*)d_in[0];
  const float* logits = (const float*)d_in[1];
  const float* w_qkv  = (const float*)d_in[2];
  const float* b_qkv  = (const float*)d_in[3];
  const float* w_out  = (const float*)d_in[4];
  const float* b_out  = (const float*)d_in[5];
  float* out = (float*)d_out;

  char* p = (char*)d_ws;
  size_t off = 0;
  auto alloc = [&](size_t bytes) {
    void* r = p + off; off += (bytes + 255) & ~(size_t)255; return r;
  };
  int* hdr              = (int*)alloc(1024);
  int* cmap             = (int*)alloc(1536 * 4);
  int* sched            = (int*)alloc(768 * 4);
  unsigned short* qbf   = (unsigned short*)alloc((size_t)8192 * 512 * 2);
  unsigned short* wqkvT = (unsigned short*)alloc((size_t)1536 * 512 * 2);
  unsigned short* woutT = (unsigned short*)alloc((size_t)512 * 512 * 2);
  unsigned short* qkpad = (unsigned short*)alloc((size_t)8192 * QKROW * 2 + 4096);
  unsigned short* vbuf  = (unsigned short*)alloc((size_t)8192 * 512 * 2);
  unsigned short* Vt    = (unsigned short*)alloc((size_t)4 * VTPAD * 2048 * 2 + 4096);
  unsigned short* attnC = (unsigned short*)alloc((size_t)8192 * 512 * 2);
  (void)ws_size; (void)in_sizes; (void)n_in; (void)out_size;

  prep_kernel<<<1, 64, 0, stream>>>(logits, hdr, cmap, sched, out + 4194304);
  conv_bf16_kernel<<<4096, 256, 0, stream>>>(query, qbf, 8192 * 512 / 4);
  convWT_kernel<<<3072, 256, 0, stream>>>(w_qkv, wqkvT, 1536);
  convWT_kernel<<<1024, 256, 0, stream>>>(w_out, woutT, 512);
  gemm_bt<1><<<dim3(12, 64), 256, 0, stream>>>(qbf, wqkvT, b_qkv, nullptr, qkpad, vbuf, cmap, 1536, 512);
  transV_kernel<<<dim3(32, 16, 4), 256, 0, stream>>>(vbuf, Vt);
  attn_staged<<<dim3(768, 1, 1), 256, 0, stream>>>(qkpad, Vt, attnC, hdr, sched);
  attn_kernel<8, 15><<<dim3(32, 6, 4), 256, 0, stream>>>(qkpad, Vt, attnC, hdr);
  gemm_bt<0><<<dim3(4, 64), 256, 0, stream>>>(attnC, woutT, b_out, out, nullptr, nullptr, nullptr, 512, 512);
}

// Round 5
// 380.813 us; speedup vs baseline: 1.7831x; 1.7831x over previous
//
#include <hip/hip_runtime.h>
#include <hip/hip_bf16.h>
#include <cstdint>

typedef __attribute__((ext_vector_type(8))) __bf16 bf16x8;
typedef __attribute__((ext_vector_type(8))) unsigned short u16x8;
typedef __attribute__((ext_vector_type(4))) float f32x4;

#define QKSTRIDE 640
#define QKROW 1280
#define VTPAD 528

static __device__ __forceinline__ unsigned short f2bf(float f) {
  __hip_bfloat16 h = __float2bfloat16(f);
  return *reinterpret_cast<unsigned short*>(&h);
}
static __device__ __forceinline__ unsigned pack2bf(float a, float b) {
  return (unsigned)f2bf(a) | ((unsigned)f2bf(b) << 16);
}

static __device__ __forceinline__ void gload_lds16(const void* g, void* lds) {
  __builtin_amdgcn_global_load_lds(
      (const __attribute__((address_space(1))) unsigned int*)g,
      (__attribute__((address_space(3))) unsigned int*)lds, 16, 0, 0);
}

// ---------------- prep: head dims, loss, column map, block schedule ----------------
__global__ void prep_kernel(const float* __restrict__ logits, int* __restrict__ hdr,
                            int* __restrict__ cmap, int* __restrict__ sched,
                            float* __restrict__ loss_out) {
  if (threadIdx.x != 0 || blockIdx.x != 0) return;
  float l[6]; float mx = -1e30f;
  for (int i = 0; i < 6; ++i) { l[i] = logits[i]; mx = fmaxf(mx, l[i]); }
  float e[6]; float s = 0.f;
  for (int i = 0; i < 6; ++i) { e[i] = expf(l[i] - mx); s += e[i]; }
  float hdf[6]; float sumh = 0.f;
  for (int i = 0; i < 6; ++i) { hdf[i] = 8.0f + (e[i] / s) * 464.0f; sumh += hdf[i]; }
  int hdi[6]; float res[6]; int isum = 0;
  for (int i = 0; i < 6; ++i) {
    float fl = floorf(hdf[i]);
    hdi[i] = (int)fl; res[i] = hdf[i] - fl; isum += hdi[i];
  }
  int diff = 512 - isum;
  bool used[6] = {false, false, false, false, false, false};
  if (diff > 0) {
    for (int t = 0; t < diff; ++t) {
      int best = -1; float bv = -1e30f;
      for (int i = 0; i < 6; ++i) if (!used[i] && res[i] > bv) { bv = res[i]; best = i; }
      used[best] = true; hdi[best] += 1;
    }
  } else if (diff < 0) {
    for (int t = 0; t < -diff; ++t) {
      int best = -1; float bv = 1e30f;
      for (int i = 0; i < 6; ++i) if (!used[i] && res[i] < bv) { bv = res[i]; best = i; }
      used[best] = true; hdi[best] -= 1;
    }
  }
  int starts[6], astarts[6];
  { int st = 0, ast = 0;
    for (int i = 0; i < 6; ++i) {
      starts[i] = st; astarts[i] = ast;
      hdr[i] = hdi[i]; hdr[8 + i] = st; hdr[16 + i] = ast;
      st += hdi[i]; ast += (hdi[i] + 7) & ~7;
    } }
  for (int col = 0; col < 512; ++col) {
    int hh = 5;
    for (int i = 0; i < 5; ++i) if (col < starts[i + 1]) { hh = i; break; }
    int qc = astarts[hh] + (col - starts[hh]);
    cmap[col] = qc;
    cmap[512 + col] = QKSTRIDE + qc;
    cmap[1024 + col] = 4096 + col;
  }
  // ---- block schedule: 24 (h,b) work-sets, LPT into 8 XCD bins of 3, big-first ----
  {
    int csth[6];
    for (int i = 0; i < 6; ++i) {
      int ncl = (hdi[i] + 31) / 32;
      int ntl = (hdi[i] + 15) / 16;
      csth[i] = 4 * ncl + 2 * ntl + 8;
    }
    int ord[6] = {0, 1, 2, 3, 4, 5};
    for (int a = 0; a < 6; ++a)
      for (int c = a + 1; c < 6; ++c)
        if (csth[ord[c]] > csth[ord[a]]) { int t = ord[a]; ord[a] = ord[c]; ord[c] = t; }
    int binload[8], bincnt[8], binh[8][3], binb[8][3];
    for (int x = 0; x < 8; ++x) { binload[x] = 0; bincnt[x] = 0; }
    for (int a = 0; a < 6; ++a)
      for (int bb = 0; bb < 4; ++bb) {
        int best = -1;
        for (int x = 0; x < 8; ++x)
          if (bincnt[x] < 3 && (best < 0 || binload[x] < binload[best])) best = x;
        binh[best][bincnt[best]] = ord[a];
        binb[best][bincnt[best]] = bb;
        binload[best] += csth[ord[a]];
        bincnt[best]++;
      }
    for (int x = 0; x < 8; ++x)
      for (int pI = 0; pI < 3; ++pI)
        for (int q = 0; q < 32; ++q)
          sched[x + 8 * (pI * 32 + q)] = binh[x][pI] | (binb[x][pI] << 4) | (q << 8);
  }
  float dv = sumh - 512.0f;
  float floss = dv * dv;
  float rsum = 0.f;
  for (int i = 0; i < 6; ++i) rsum += fmaxf(8.0f - hdf[i], 0.0f);
  floss += rsum / 6.0f;
  float il = 0.f;
  for (int i = 0; i < 6; ++i) { float dd = hdf[i] - (float)hdi[i]; il += dd * dd; }
  il /= 6.0f;
  loss_out[0] = floss + 0.5f * il;
}

// ---------------- converters ----------------
__global__ void conv_bf16_kernel(const float* __restrict__ x, unsigned short* __restrict__ y, int n4) {
  int i = blockIdx.x * blockDim.x + threadIdx.x;
  if (i >= n4) return;
  float4 v = reinterpret_cast<const float4*>(x)[i];
  union { unsigned short u[4]; uint2 q; } o;
  o.u[0] = f2bf(v.x); o.u[1] = f2bf(v.y); o.u[2] = f2bf(v.z); o.u[3] = f2bf(v.w);
  reinterpret_cast<uint2*>(y)[i] = o.q;
}

__global__ void convWT_kernel(const float* __restrict__ W, unsigned short* __restrict__ WT, int N) {
  int idx = blockIdx.x * blockDim.x + threadIdx.x;
  if (idx >= N * 512) return;
  int k = idx & 511, n = idx >> 9;
  WT[idx] = f2bf(W[(size_t)k * N + n]);
}

// ---------------- GEMM: C[M][N] = A[M][K](bf16) @ Bt[N][K]^T + bias ----------------
template<int MODE>
__global__ __launch_bounds__(256, 2) void gemm_bt(
    const unsigned short* __restrict__ A,
    const unsigned short* __restrict__ Bt,
    const float* __restrict__ bias,
    float* __restrict__ Cf,
    unsigned short* __restrict__ qkpad,
    unsigned short* __restrict__ vbuf,
    const int* __restrict__ cmap,
    int N, int K)
{
  __shared__ unsigned short As[128 * 32];
  __shared__ unsigned short Bs[128 * 32];
  const int tid = threadIdx.x;
  const int wave = tid >> 6, lane = tid & 63;
  const int lrow = lane & 15, lgrp = lane >> 4;
  const int wm = wave >> 1, wn = wave & 1;
  const int brow = blockIdx.y * 128;
  const int bcol = blockIdx.x * 128;

  f32x4 acc[4][4];
#pragma unroll
  for (int m = 0; m < 4; ++m)
#pragma unroll
    for (int n = 0; n < 4; ++n) acc[m][n] = (f32x4){0.f, 0.f, 0.f, 0.f};

  const int sig0 = wave * 128 + lane;
  for (int kb = 0; kb < K; kb += 32) {
    __syncthreads();
#pragma unroll
    for (int it = 0; it < 2; ++it) {
      const int sigma = sig0 + it * 64;
      const int r = sigma >> 2, sp = sigma & 3;
      const int sl = sp ^ ((r >> 1) & 3);
      gload_lds16(&A[(size_t)(brow + r) * K + kb + sl * 8], &As[sigma * 8]);
    }
#pragma unroll
    for (int it = 0; it < 2; ++it) {
      const int sigma = sig0 + it * 64;
      const int r = sigma >> 2, sp = sigma & 3;
      const int sl = sp ^ ((r >> 1) & 3);
      gload_lds16(&Bt[(size_t)(bcol + r) * K + kb + sl * 8], &Bs[sigma * 8]);
    }
    __syncthreads();
    const int sub = (lgrp ^ ((lrow >> 1) & 3)) * 8;
    bf16x8 aF[4], bF[4];
#pragma unroll
    for (int m = 0; m < 4; ++m)
      aF[m] = *reinterpret_cast<const bf16x8*>(&As[(wm * 64 + m * 16 + lrow) * 32 + sub]);
#pragma unroll
    for (int n = 0; n < 4; ++n)
      bF[n] = *reinterpret_cast<const bf16x8*>(&Bs[(wn * 64 + n * 16 + lrow) * 32 + sub]);
#pragma unroll
    for (int m = 0; m < 4; ++m)
#pragma unroll
      for (int n = 0; n < 4; ++n)
        acc[m][n] = __builtin_amdgcn_mfma_f32_16x16x32_bf16(aF[m], bF[n], acc[m][n], 0, 0, 0);
  }

#pragma unroll
  for (int n = 0; n < 4; ++n) {
    const int col = bcol + wn * 64 + n * 16 + lrow;
    const float bv = bias[col];
    int mc = 0;
    if (MODE == 1) mc = cmap[col];
#pragma unroll
    for (int m = 0; m < 4; ++m) {
#pragma unroll
      for (int r = 0; r < 4; ++r) {
        const int row = brow + wm * 64 + m * 16 + lgrp * 4 + r;
        const float v = acc[m][n][r] + bv;
        if (MODE == 0) {
          Cf[(size_t)row * N + col] = v;
        } else {
          if (mc < 4096) qkpad[(size_t)row * QKROW + mc] = f2bf(v);
          else vbuf[(size_t)row * 512 + (mc - 4096)] = f2bf(v);
        }
      }
    }
  }
}

// ---------------- V transpose ----------------
__global__ void transV_kernel(const unsigned short* __restrict__ vbuf, unsigned short* __restrict__ Vt) {
  __shared__ unsigned short tile[64][33];
  const int b = blockIdx.z, c0 = blockIdx.y * 32, t0 = blockIdx.x * 64;
  const int i = threadIdx.x;
  {
    int r = i >> 2, cc = (i & 3) * 8;
    u16x8 v = *reinterpret_cast<const u16x8*>(&vbuf[(size_t)(b * 2048 + t0 + r) * 512 + c0 + cc]);
#pragma unroll
    for (int j = 0; j < 8; ++j) tile[r][cc + j] = v[j];
  }
  __syncthreads();
  {
    int c = i >> 3, tt = (i & 7) * 8;
    u16x8 v;
#pragma unroll
    for (int j = 0; j < 8; ++j) v[j] = tile[tt + j][c];
    *reinterpret_cast<u16x8*>(&Vt[(size_t)(b * VTPAD + c0 + c) * 2048 + t0 + tt]) = v;
  }
}

// ---------------- flash attention: swapped QK^T, per-NC template, K-only LDS ----------------
// Per iter (32 k): [stage next K tile] -> QK(LDS K, reg Q) -> in-reg softmax
// (2 shfl) -> P bounce -> PV (V direct from global/L2, batched 8) -> __syncthreads.
template<int NC>
static __device__ __forceinline__ void attn_body(
    const unsigned short* __restrict__ qkpad,
    const unsigned short* __restrict__ Vt,
    unsigned short* __restrict__ attnC,
    int b, int q0, int d, int start, int astart,
    unsigned char* KsB, unsigned int* PlW,
    int wave, int lane)
{
  constexpr int S = (4 * NC + 7) & ~7;     // K 16B-slots per row
  constexpr int NT2 = 2 * NC;              // max d-tiles
  constexpr int KI = S / 8;                // K-stage instrs per wave
  constexpr int KTILE = 32 * S * 16;       // bytes per K buffer
  const int ntiles = (d + 15) >> 4;
  const int lrow = lane & 15, lgrp = lane >> 4;
  const float scale = 1.0f / sqrtf((float)d);

  // ---- Q fragments (B-operand: col=q=lrow, k-elems d = dc*32 + lgrp*8 + j) ----
  bf16x8 qf[NC];
  {
    const unsigned short* qp = qkpad + (size_t)(b * 2048 + q0 + lrow) * QKROW + astart + lgrp * 8;
#pragma unroll
    for (int dc = 0; dc < NC; ++dc) {
      bf16x8 v = *reinterpret_cast<const bf16x8*>(qp + dc * 32);
#pragma unroll
      for (int j = 0; j < 8; ++j)
        if (dc * 32 + lgrp * 8 + j >= d) v[j] = (__bf16)0.0f;
      qf[dc] = v;
    }
  }

  // ---- K staging addresses (linear LDS dst = uniform + lane*16; pre-swizzled src) ----
  const unsigned short* kPtr[KI];
  int kDstB[KI];
#pragma unroll
  for (int j = 0; j < KI; ++j) {
    const int g = (wave * KI + j) * 64 + lane;
    const int r = g / S, pp = g - r * S;
    const int sp = pp ^ (r & 7);
    kPtr[j] = qkpad + (size_t)(b * 2048 + r) * QKROW + QKSTRIDE + astart + sp * 8;
    kDstB[j] = g * 16;
  }

  const unsigned short* vRow = Vt + (size_t)(b * VTPAD + start + lrow) * 2048 + lgrp * 8;

  f32x4 acc[NT2];
#pragma unroll
  for (int t = 0; t < NT2; ++t) acc[t] = (f32x4){0.f, 0.f, 0.f, 0.f};
  float m_run = -1e30f, l_run = 0.f;       // per-lane: own q-row = lane&15

  // prologue: stage kt=0 into buf0
#pragma unroll
  for (int j = 0; j < KI; ++j) gload_lds16(kPtr[j], KsB + kDstB[j]);
#pragma unroll
  for (int j = 0; j < KI; ++j) kPtr[j] += 32 * QKROW;
  __syncthreads();

  for (int i = 0; i < 64; ++i) {
    const int kt = i << 5;
    const int cur = i & 1;
    if (i < 63) {
      unsigned char* kd = KsB + (cur ^ 1) * KTILE;
#pragma unroll
      for (int j = 0; j < KI; ++j) gload_lds16(kPtr[j], kd + kDstB[j]);
#pragma unroll
      for (int j = 0; j < KI; ++j) kPtr[j] += 32 * QKROW;
    }

    // ---- QK^T swapped: s = K x Q; lane: q-col = lrow, k-row = 16t + lgrp*4 + r ----
    f32x4 s4[2];
    s4[0] = (f32x4){0.f, 0.f, 0.f, 0.f};
    s4[1] = (f32x4){0.f, 0.f, 0.f, 0.f};
    const unsigned char* kB = KsB + cur * KTILE;
    const int swz = lrow & 7;
    __builtin_amdgcn_s_setprio(1);
#pragma unroll
    for (int dc = 0; dc < NC; ++dc) {
#pragma unroll
      for (int t = 0; t < 2; ++t) {
        const bf16x8 kf = *reinterpret_cast<const bf16x8*>(
            kB + (t * 16 + lrow) * (S * 16) + (((dc * 4 + lgrp) ^ swz) * 16));
        s4[t] = __builtin_amdgcn_mfma_f32_16x16x32_bf16(kf, qf[dc], s4[t], 0, 0, 0);
      }
    }
    __builtin_amdgcn_s_setprio(0);

    // ---- in-register online softmax (defer-max THR=8; 2 shfl per reduce) ----
    float ps[8];
#pragma unroll
    for (int t = 0; t < 2; ++t)
#pragma unroll
      for (int r = 0; r < 4; ++r) ps[t * 4 + r] = s4[t][r] * scale;
    float pm = ps[0];
#pragma unroll
    for (int z = 1; z < 8; ++z) pm = fmaxf(pm, ps[z]);
    pm = fmaxf(pm, __shfl_xor(pm, 16));
    pm = fmaxf(pm, __shfl_xor(pm, 32));
    if (__any(pm > m_run + 8.0f)) {
      const float mn = fmaxf(m_run, pm);
      const float alpha = __expf(m_run - mn);
      m_run = mn; l_run *= alpha;
      float al4[4];
#pragma unroll
      for (int r = 0; r < 4; ++r) al4[r] = __shfl(alpha, lgrp * 4 + r);
#pragma unroll
      for (int t = 0; t < NT2; ++t) {
        if (t < ntiles) {
#pragma unroll
          for (int r = 0; r < 4; ++r) acc[t][r] *= al4[r];
        }
      }
    }
    float sum = 0.f;
#pragma unroll
    for (int z = 0; z < 8; ++z) { ps[z] = __expf(ps[z] - m_run); sum += ps[z]; }
    sum += __shfl_xor(sum, 16);
    sum += __shfl_xor(sum, 32);
    l_run += sum;

    // ---- P bounce: write k=16t+4*lgrp+r at own row lrow; read A-frag k=lgrp*8+j ----
#pragma unroll
    for (int t = 0; t < 2; ++t) {
      uint2 w;
      w.x = pack2bf(ps[t * 4 + 0], ps[t * 4 + 1]);
      w.y = pack2bf(ps[t * 4 + 2], ps[t * 4 + 3]);
      *reinterpret_cast<uint2*>(PlW + lrow * 20 + 8 * t + 2 * lgrp) = w;
    }
    asm volatile("s_waitcnt lgkmcnt(0)" ::: "memory");
    __builtin_amdgcn_sched_barrier(0);
    const bf16x8 pa = *reinterpret_cast<const bf16x8*>(PlW + lrow * 20 + 4 * lgrp);

    // ---- PV: V direct (L2), batched loads of 8 tiles, then MFMA ----
#pragma unroll
    for (int t0 = 0; t0 < NT2; t0 += 8) {
      bf16x8 vf[8];
#pragma unroll
      for (int j = 0; j < 8; ++j) {
        const int t = t0 + j;
        if (t < NT2 && t < ntiles)
          vf[j] = *reinterpret_cast<const bf16x8*>(vRow + (size_t)t * 32768 + kt);
      }
      __builtin_amdgcn_s_setprio(1);
#pragma unroll
      for (int j = 0; j < 8; ++j) {
        const int t = t0 + j;
        if (t < NT2 && t < ntiles)
          acc[t] = __builtin_amdgcn_mfma_f32_16x16x32_bf16(pa, vf[j], acc[t], 0, 0, 0);
      }
      __builtin_amdgcn_s_setprio(0);
    }
    __syncthreads();
  }

  // ---- epilogue: acc row q = lgrp*4+r, col d = t*16 + lrow ----
  float invl[4];
#pragma unroll
  for (int r = 0; r < 4; ++r) invl[r] = 1.0f / __shfl(l_run, lgrp * 4 + r);
#pragma unroll
  for (int t = 0; t < NT2; ++t) {
    if (t < ntiles) {
      const int col = t * 16 + lrow;
      if (col < d) {
#pragma unroll
        for (int r = 0; r < 4; ++r) {
          attnC[(size_t)(b * 2048 + q0 + lgrp * 4 + r) * 512 + start + col] =
              f2bf(acc[t][r] * invl[r]);
        }
      }
    }
  }
}

__global__ __launch_bounds__(256, 3) void attn_staged(
    const unsigned short* __restrict__ qkpad,
    const unsigned short* __restrict__ Vt,
    unsigned short* __restrict__ attnC,
    const int* __restrict__ hdr,
    const int* __restrict__ sched)
{
  __shared__ __align__(16) unsigned char KsB[32768];   // 2 x (32 rows x S slots x 16B)
  __shared__ unsigned int Pl[4][16 * 20];              // per-wave P bounce

  const int sv = sched[blockIdx.x];
  const int h = sv & 15, b = (sv >> 4) & 15, qb = sv >> 8;
  const int d = hdr[h];
  const int nc = (d + 31) >> 5;
  if (nc > 8) return;
  const int start = hdr[8 + h];
  const int astart = hdr[16 + h];
  const int wave = threadIdx.x >> 6, lane = threadIdx.x & 63;
  const int q0 = qb * 64 + wave * 16;

  unsigned int* PlW = &Pl[wave][0];
  switch (nc) {
    case 1: attn_body<1>(qkpad, Vt, attnC, b, q0, d, start, astart, KsB, PlW, wave, lane); break;
    case 2: attn_body<2>(qkpad, Vt, attnC, b, q0, d, start, astart, KsB, PlW, wave, lane); break;
    case 3: attn_body<3>(qkpad, Vt, attnC, b, q0, d, start, astart, KsB, PlW, wave, lane); break;
    case 4: attn_body<4>(qkpad, Vt, attnC, b, q0, d, start, astart, KsB, PlW, wave, lane); break;
    case 5: attn_body<5>(qkpad, Vt, attnC, b, q0, d, start, astart, KsB, PlW, wave, lane); break;
    case 6: attn_body<6>(qkpad, Vt, attnC, b, q0, d, start, astart, KsB, PlW, wave, lane); break;
    case 7: attn_body<7>(qkpad, Vt, attnC, b, q0, d, start, astart, KsB, PlW, wave, lane); break;
    case 8: attn_body<8>(qkpad, Vt, attnC, b, q0, d, start, astart, KsB, PlW, wave, lane); break;
    default: break;
  }
}

// ---------------- direct fallback for nc>8 (d>256), normally all-exit ----------------
template<int NCLO, int NCHI>
__global__ __launch_bounds__(256, 2) void attn_kernel(
    const unsigned short* __restrict__ qkpad,
    const unsigned short* __restrict__ Vt,
    unsigned short* __restrict__ attnC,
    const int* __restrict__ hdr)
{
  const int h = blockIdx.y, b = blockIdx.z;
  const int d = hdr[h];
  const int nc = (d + 31) >> 5;
  if (nc <= NCLO || nc > NCHI) return;
  const int start = hdr[8 + h];
  const int astart = hdr[16 + h];
  const int wave = threadIdx.x >> 6;
  const int lane = threadIdx.x & 63;
  const int lrow = lane & 15, lgrp = lane >> 4;
  const int q0 = blockIdx.x * 64 + wave * 16;
  const int ntiles = (d + 15) >> 4;
  const float scale = 1.0f / sqrtf((float)d);

  __shared__ unsigned short Pl[2][4][16 * 32];

  bf16x8 qf[NCHI];
  {
    const size_t qbase = (size_t)(b * 2048 + q0 + lrow) * QKROW + astart;
#pragma unroll
    for (int dc = 0; dc < NCHI; ++dc) {
      if (dc < nc) {
        bf16x8 v = *reinterpret_cast<const bf16x8*>(&qkpad[qbase + dc * 32 + lgrp * 8]);
#pragma unroll
        for (int j = 0; j < 8; ++j)
          if (dc * 32 + lgrp * 8 + j >= d) v[j] = (__bf16)0.0f;
        qf[dc] = v;
      }
    }
  }

  f32x4 acc[2 * NCHI];
#pragma unroll
  for (int t = 0; t < 2 * NCHI; ++t) acc[t] = (f32x4){0.f, 0.f, 0.f, 0.f};
  float m_run[4] = {-1e30f, -1e30f, -1e30f, -1e30f};
  float l_run[4] = {0.f, 0.f, 0.f, 0.f};

  for (int kt = 0; kt < 2048; kt += 32) {
    f32x4 s0 = {0.f, 0.f, 0.f, 0.f}, s1 = {0.f, 0.f, 0.f, 0.f};
    const size_t kb0 = (size_t)(b * 2048 + kt + lrow) * QKROW + QKSTRIDE + astart;
    const size_t kb1 = kb0 + (size_t)16 * QKROW;
#pragma unroll
    for (int dc = 0; dc < NCHI; ++dc) {
      if (dc < nc) {
        bf16x8 k0 = *reinterpret_cast<const bf16x8*>(&qkpad[kb0 + dc * 32 + lgrp * 8]);
        bf16x8 k1 = *reinterpret_cast<const bf16x8*>(&qkpad[kb1 + dc * 32 + lgrp * 8]);
        s0 = __builtin_amdgcn_mfma_f32_16x16x32_bf16(qf[dc], k0, s0, 0, 0, 0);
        s1 = __builtin_amdgcn_mfma_f32_16x16x32_bf16(qf[dc], k1, s1, 0, 0, 0);
      }
    }
    float p0[4], p1[4], pmax[4];
#pragma unroll
    for (int r = 0; r < 4; ++r) {
      p0[r] = s0[r] * scale; p1[r] = s1[r] * scale;
      float mx = fmaxf(p0[r], p1[r]);
#pragma unroll
      for (int off = 1; off < 16; off <<= 1) mx = fmaxf(mx, __shfl_xor(mx, off));
      pmax[r] = mx;
    }
    bool need = false;
#pragma unroll
    for (int r = 0; r < 4; ++r) need = need || (pmax[r] > m_run[r] + 8.0f);
    if (__any(need)) {
#pragma unroll
      for (int r = 0; r < 4; ++r) {
        float mn = fmaxf(m_run[r], pmax[r]);
        float al = __expf(m_run[r] - mn);
        m_run[r] = mn; l_run[r] *= al;
#pragma unroll
        for (int t = 0; t < 2 * NCHI; ++t)
          if (t < ntiles) acc[t][r] *= al;
      }
    }
#pragma unroll
    for (int r = 0; r < 4; ++r) {
      p0[r] = __expf(p0[r] - m_run[r]);
      p1[r] = __expf(p1[r] - m_run[r]);
      float sm = p0[r] + p1[r];
#pragma unroll
      for (int off = 1; off < 16; off <<= 1) sm += __shfl_xor(sm, off);
      l_run[r] += sm;
    }
    const int pb = (kt >> 5) & 1;
    unsigned short* P = &Pl[pb][wave][0];
#pragma unroll
    for (int r = 0; r < 4; ++r) {
      P[(lgrp * 4 + r) * 32 + lrow] = f2bf(p0[r]);
      P[(lgrp * 4 + r) * 32 + 16 + lrow] = f2bf(p1[r]);
    }
    asm volatile("s_waitcnt lgkmcnt(0)" ::: "memory");
    bf16x8 pf = *reinterpret_cast<const bf16x8*>(&P[lrow * 32 + lgrp * 8]);
    const size_t vbase = (size_t)(b * VTPAD + start) * 2048 + kt + lgrp * 8;
#pragma unroll
    for (int t = 0; t < 2 * NCHI; ++t) {
      if (t < ntiles) {
        bf16x8 vf = *reinterpret_cast<const bf16x8*>(&Vt[vbase + (size_t)(t * 16 + lrow) * 2048]);
        acc[t] = __builtin_amdgcn_mfma_f32_16x16x32_bf16(pf, vf, acc[t], 0, 0, 0);
      }
    }
  }

  float inv[4];
#pragma unroll
  for (int r = 0; r < 4; ++r) inv[r] = 1.0f / l_run[r];
#pragma unroll
  for (int t = 0; t < 2 * NCHI; ++t) {
    if (t < ntiles) {
      int col = t * 16 + lrow;
      if (col < d) {
#pragma unroll
        for (int r = 0; r < 4; ++r) {
          attnC[(size_t)(b * 2048 + q0 + lgrp * 4 + r) * 512 + start + col] =
              f2bf(acc[t][r] * inv[r]);
        }
      }
    }
  }
}

// ---------------- launch ----------------
extern "C" void kernel_launch(void* const* d_in, const int* in_sizes, int n_in,
                              void* d_out, int out_size, void* d_ws, size_t ws_size,
                              hipStream_t stream) {
  const float* query  = (const float*)d_in[0];
  const float* logits = (const float*)d_in[1];
  const float* w_qkv  = (const float*)d_in[2];
  const float* b_qkv  = (const float*)d_in[3];
  const float* w_out  = (const float*)d_in[4];
  const float* b_out  = (const float*)d_in[5];
  float* out = (float*)d_out;

  char* p = (char*)d_ws;
  size_t off = 0;
  auto alloc = [&](size_t bytes) {
    void* r = p + off; off += (bytes + 255) & ~(size_t)255; return r;
  };
  int* hdr              = (int*)alloc(1024);
  int* cmap             = (int*)alloc(1536 * 4);
  int* sched            = (int*)alloc(768 * 4);
  unsigned short* qbf   = (unsigned short*)alloc((size_t)8192 * 512 * 2);
  unsigned short* wqkvT = (unsigned short*)alloc((size_t)1536 * 512 * 2);
  unsigned short* woutT = (unsigned short*)alloc((size_t)512 * 512 * 2);
  unsigned short* qkpad = (unsigned short*)alloc((size_t)8192 * QKROW * 2 + 4096);
  unsigned short* vbuf  = (unsigned short*)alloc((size_t)8192 * 512 * 2);
  unsigned short* Vt    = (unsigned short*)alloc((size_t)4 * VTPAD * 2048 * 2 + 4096);
  unsigned short* attnC = (unsigned short*)alloc((size_t)8192 * 512 * 2);
  (void)ws_size; (void)in_sizes; (void)n_in; (void)out_size;

  prep_kernel<<<1, 64, 0, stream>>>(logits, hdr, cmap, sched, out + 4194304);
  conv_bf16_kernel<<<4096, 256, 0, stream>>>(query, qbf, 8192 * 512 / 4);
  convWT_kernel<<<3072, 256, 0, stream>>>(w_qkv, wqkvT, 1536);
  convWT_kernel<<<1024, 256, 0, stream>>>(w_out, woutT, 512);
  gemm_bt<1><<<dim3(12, 64), 256, 0, stream>>>(qbf, wqkvT, b_qkv, nullptr, qkpad, vbuf, cmap, 1536, 512);
  transV_kernel<<<dim3(32, 16, 4), 256, 0, stream>>>(vbuf, Vt);
  attn_staged<<<dim3(768, 1, 1), 256, 0, stream>>>(qkpad, Vt, attnC, hdr, sched);
  attn_kernel<8, 15><<<dim3(32, 6, 4), 256, 0, stream>>>(qkpad, Vt, attnC, hdr);
  gemm_bt<0><<<dim3(4, 64), 256, 0, stream>>>(attnC, woutT, b_out, out, nullptr, nullptr, nullptr, 512, 512);
}